// Round 7
// baseline (176.973 us; speedup 1.0000x reference)
//
#include <hip/hip_runtime.h>
#include <math.h>

#define NROWS 8192
#define HALF  4096
#define EMB   2048
#define DIM   256
#define INV_T 10.0f

typedef __bf16 bf16x8v __attribute__((ext_vector_type(8)));
typedef __bf16 bf16x4v __attribute__((ext_vector_type(4)));
typedef float  f32x4   __attribute__((ext_vector_type(4)));

__device__ __forceinline__ void gld_lds16(const void* g, void* l) {
    __builtin_amdgcn_global_load_lds((const __attribute__((address_space(1))) void*)g,
                                     (__attribute__((address_space(3))) void*)l,
                                     16, 0, 0);
}

// ---------- K0: W transpose->bf16, PLUS zero total/out ----------
__global__ __launch_bounds__(256) void wt_kernel(const float* __restrict__ W,
                                                 __bf16* __restrict__ Wt,
                                                 float* __restrict__ total,
                                                 float* __restrict__ out) {
    __shared__ __bf16 t[64][72];
    const int n0 = blockIdx.x * 64;
    const int k0 = blockIdx.y * 64;
    const int tid = threadIdx.x;
    const int c = tid & 63;
    const int rr = tid >> 6;

    const int b = blockIdx.y * 4 + blockIdx.x;
    if (tid < 64) total[b * 64 + tid] = 0.f;
    if (b == 0 && tid == 0) out[0] = 0.f;

#pragma unroll
    for (int it = 0; it < 16; it++) {
        int k = it * 4 + rr;
        t[k][c] = (__bf16)W[(size_t)(k0 + k) * DIM + n0 + c];
    }
    __syncthreads();
#pragma unroll
    for (int it = 0; it < 16; it++) {
        int n = it * 4 + rr;
        Wt[(size_t)(n0 + n) * EMB + k0 + c] = t[c][n];
    }
}

// ---------- K1: fused GEMM + bias + L2-normalize, BARRIER-FREE K-loop.
//   MFMA fragments loaded directly global->VGPR (no LDS, no __syncthreads in
//   the loop => no vmcnt(0) drains; each wave pipelines independently with a
//   1-ahead register rotation). 32 rows x 256 cols per block, grid 256. ----------
__global__ __launch_bounds__(256, 1) void gemm_norm_bf(
    const float* __restrict__ A,      // [8192][2048] f32
    const __bf16* __restrict__ Wt,    // [256][2048] bf16 (W^T)
    const float* __restrict__ bias,   // [256]
    __bf16* __restrict__ outb)        // [8192][256] bf16 normalized
{
    __shared__ float ns[32][4];
    __shared__ float inv_sh[32];
    __shared__ __bf16 c_sh[32 * DIM];   // 16 KB store-staging

    const int tid  = threadIdx.x;
    const int wave = tid >> 6, lane = tid & 63;
    const int quad = lane >> 4, l15 = lane & 15;
    const int rowBase = blockIdx.x * 32;
    const int waveCol = wave * 64;

    // per-lane fragment base pointers (A row-major, Wt K-contiguous)
    const float*  abase = A  + (size_t)(rowBase + l15) * EMB + quad * 8;
    const __bf16* bbase = Wt + (size_t)(waveCol + l15) * EMB + quad * 8;

    f32x4 acc[2][4];
    const f32x4 zero = {0.f, 0.f, 0.f, 0.f};
#pragma unroll
    for (int m = 0; m < 2; m++)
#pragma unroll
        for (int n = 0; n < 4; n++) acc[m][n] = zero;

    // prefetch iter 0
    f32x4   a_cur[2][2];
    bf16x8v b_cur[4];
#pragma unroll
    for (int m = 0; m < 2; m++) {
        a_cur[m][0] = *(const f32x4*)(abase + (size_t)m * 16 * EMB);
        a_cur[m][1] = *(const f32x4*)(abase + (size_t)m * 16 * EMB + 4);
    }
#pragma unroll
    for (int n = 0; n < 4; n++)
        b_cur[n] = *(const bf16x8v*)(bbase + (size_t)n * 16 * EMB);

    for (int k0 = 0; k0 < EMB; k0 += 32) {
        const int k1 = (k0 + 32) & (EMB - 1);   // wraps to 0 on last iter (harmless)
        f32x4   a_nxt[2][2];
        bf16x8v b_nxt[4];
#pragma unroll
        for (int m = 0; m < 2; m++) {
            a_nxt[m][0] = *(const f32x4*)(abase + (size_t)m * 16 * EMB + k1);
            a_nxt[m][1] = *(const f32x4*)(abase + (size_t)m * 16 * EMB + k1 + 4);
        }
#pragma unroll
        for (int n = 0; n < 4; n++)
            b_nxt[n] = *(const bf16x8v*)(bbase + (size_t)n * 16 * EMB + k1);

        // convert current A fp32 -> bf16 frags
        bf16x8v af[2];
#pragma unroll
        for (int m = 0; m < 2; m++)
#pragma unroll
            for (int i = 0; i < 4; i++) {
                af[m][i]     = (__bf16)a_cur[m][0][i];
                af[m][4 + i] = (__bf16)a_cur[m][1][i];
            }
#pragma unroll
        for (int m = 0; m < 2; m++)
#pragma unroll
            for (int n = 0; n < 4; n++)
                acc[m][n] = __builtin_amdgcn_mfma_f32_16x16x32_bf16(af[m], b_cur[n], acc[m][n], 0, 0, 0);

#pragma unroll
        for (int m = 0; m < 2; m++) { a_cur[m][0] = a_nxt[m][0]; a_cur[m][1] = a_nxt[m][1]; }
#pragma unroll
        for (int n = 0; n < 4; n++) b_cur[n] = b_nxt[n];
    }

    // ---- epilogue: bias, row sum-of-squares, normalize, coalesced bf16 store ----
    float bv[4];
#pragma unroll
    for (int n = 0; n < 4; n++) bv[n] = bias[waveCol + n * 16 + l15];

    float vals[2][4][4];
    float ssl[2][4];
#pragma unroll
    for (int m = 0; m < 2; m++)
#pragma unroll
        for (int r = 0; r < 4; r++) ssl[m][r] = 0.f;
#pragma unroll
    for (int m = 0; m < 2; m++)
#pragma unroll
        for (int n = 0; n < 4; n++)
#pragma unroll
            for (int r = 0; r < 4; r++) {
                float v = acc[m][n][r] + bv[n];
                vals[m][n][r] = v;
                ssl[m][r] += v * v;
            }
    // reduce over the 16 l15-lanes (cols) — stays within quad-group
#pragma unroll
    for (int off = 1; off < 16; off <<= 1)
#pragma unroll
        for (int m = 0; m < 2; m++)
#pragma unroll
            for (int r = 0; r < 4; r++) ssl[m][r] += __shfl_xor(ssl[m][r], off, 64);
    if (l15 == 0)
#pragma unroll
        for (int m = 0; m < 2; m++)
#pragma unroll
            for (int r = 0; r < 4; r++)
                ns[m * 16 + quad * 4 + r][wave] = ssl[m][r];
    __syncthreads();
    if (tid < 32) {
        float s = ns[tid][0] + ns[tid][1] + ns[tid][2] + ns[tid][3];
        inv_sh[tid] = 1.f / fmaxf(sqrtf(s), 1e-12f);
    }
    __syncthreads();
#pragma unroll
    for (int m = 0; m < 2; m++)
#pragma unroll
        for (int n = 0; n < 4; n++)
#pragma unroll
            for (int r = 0; r < 4; r++) {
                int row = m * 16 + quad * 4 + r;
                c_sh[row * DIM + waveCol + n * 16 + l15] =
                    (__bf16)(vals[m][n][r] * inv_sh[row]);
            }
    __syncthreads();
    const int4* src = (const int4*)c_sh;
    int4* dst = (int4*)(outb + (size_t)rowBase * DIM);
#pragma unroll
    for (int it = 0; it < 4; it++) dst[it * 256 + tid] = src[it * 256 + tid];
}

// ---------- K2: sim = X@X^T. BK=64 streaming, 32 KB LDS, shuffle-free epilogue ----------
#define TILE 128
#define NTILE (NROWS / TILE)              // 64
#define NBLK  (NTILE * (NTILE + 1) / 2)   // 2080

__global__ __launch_bounds__(256, 3) void sim_kernel(
    const __bf16* __restrict__ X,
    float* __restrict__ total,
    float* __restrict__ posv)
{
    __shared__ __align__(16) char smem[32768];
    __bf16* a_base = (__bf16*)smem;            // [2][128][32]
    __bf16* b_base = (__bf16*)(smem + 16384);  // [2][128][32]
    float*  rs     = (float*)smem;             // [128][2][16] = 16 KB
    float*  cs     = (float*)(smem + 16384);   // [128][2][4]  = 4 KB

    const int t = blockIdx.x;
    int bx = (int)((129.0 - sqrt(16641.0 - 8.0 * (double)t)) * 0.5);
    while (64 * (bx + 1) - ((bx + 1) * bx) / 2 <= t) bx++;
    while (64 * bx - (bx * (bx - 1)) / 2 > t) bx--;
    const int by = bx + (t - (64 * bx - (bx * (bx - 1)) / 2));
    const bool diag = (bx == by);

    const int tid  = threadIdx.x;
    const int wave = tid >> 6, lane = tid & 63;
    const int quad = lane >> 4, l15 = lane & 15;
    const int rowBase = bx * TILE;
    const int colBase = by * TILE;
    const int waveRow = (wave >> 1) * 64;
    const int waveCol = (wave & 1) * 64;

    f32x4 acc[4][4];
    const f32x4 zero = {0.f, 0.f, 0.f, 0.f};
#pragma unroll
    for (int m = 0; m < 4; m++)
#pragma unroll
        for (int n = 0; n < 4; n++) acc[m][n] = zero;

    const int r16 = lane >> 2;
    const int b4  = lane & 3;

    for (int k0 = 0; k0 < DIM; k0 += 64) {
        __syncthreads();
#pragma unroll
        for (int c = 0; c < 2; c++) {
#pragma unroll
            for (int j = 0; j < 2; j++) {
                int rg = wave * 2 + j;
                const __bf16* asrc = X + (size_t)(rowBase + rg * 16 + r16) * DIM + k0 + c * 32 + b4 * 8;
                const __bf16* bsrc = X + (size_t)(colBase + rg * 16 + r16) * DIM + k0 + c * 32 + b4 * 8;
                gld_lds16(asrc, a_base + (c * TILE + rg * 16) * 32);
                gld_lds16(bsrc, b_base + (c * TILE + rg * 16) * 32);
            }
        }
        __syncthreads();
#pragma unroll
        for (int ks = 0; ks < 2; ks++) {
            bf16x8v af[4], bfv[4];
#pragma unroll
            for (int m = 0; m < 4; m++)
                af[m] = *(const bf16x8v*)(a_base + (ks * TILE + waveRow + m * 16 + l15) * 32 + quad * 8);
#pragma unroll
            for (int n = 0; n < 4; n++)
                bfv[n] = *(const bf16x8v*)(b_base + (ks * TILE + waveCol + n * 16 + l15) * 32 + quad * 8);
#pragma unroll
            for (int m = 0; m < 4; m++)
#pragma unroll
                for (int n = 0; n < 4; n++)
                    acc[m][n] = __builtin_amdgcn_mfma_f32_16x16x32_bf16(af[m], bfv[n], acc[m][n], 0, 0, 0);
        }
    }

    float es[4][4];
    float ecol[4];
#pragma unroll
    for (int n = 0; n < 4; n++) ecol[n] = 0.f;
#pragma unroll
    for (int m = 0; m < 4; m++) {
#pragma unroll
        for (int r = 0; r < 4; r++) {
            int grow = rowBase + waveRow + m * 16 + quad * 4 + r;
            float e_acc = 0.f;
#pragma unroll
            for (int n = 0; n < 4; n++) {
                int gcol = colBase + waveCol + n * 16 + l15;
                float s = acc[m][n][r];
                if (gcol - grow == HALF) { posv[grow] = s; posv[gcol] = s; }
                float e = (gcol == grow) ? 0.f : __expf(s * INV_T);
                e_acc += e;
                ecol[n] += e;
            }
            es[m][r] = e_acc;
        }
    }

    __syncthreads();
    const int wc = wave & 1;
    const int wr = wave >> 1;
#pragma unroll
    for (int m = 0; m < 4; m++)
#pragma unroll
        for (int r = 0; r < 4; r++) {
            int lrow = waveRow + m * 16 + quad * 4 + r;
            rs[(lrow * 2 + wc) * 16 + l15] = es[m][r];
        }
    if (!diag) {
#pragma unroll
        for (int n = 0; n < 4; n++) {
            int lcol = waveCol + n * 16 + l15;
            cs[(lcol * 2 + wr) * 4 + quad] = ecol[n];
        }
    }
    __syncthreads();

    if (tid < TILE) {
        float rsum = 0.f;
#pragma unroll
        for (int i = 0; i < 32; i++) rsum += rs[tid * 32 + i];
        atomicAdd(&total[rowBase + tid], rsum);
        if (!diag) {
            float csum = 0.f;
#pragma unroll
            for (int i = 0; i < 8; i++) csum += cs[tid * 8 + i];
            atomicAdd(&total[colBase + tid], csum);
        }
    }
}

// ---------- K3: loss ----------
__global__ __launch_bounds__(256) void loss_kernel(
    const float* __restrict__ total, const float* __restrict__ posv,
    float* __restrict__ out)
{
    __shared__ float red[4];
    const int tid = threadIdx.x;
    const int i = blockIdx.x * 256 + tid;
    float s = posv[i] * INV_T - __logf(total[i]);
#pragma unroll
    for (int off = 1; off < 64; off <<= 1) s += __shfl_xor(s, off, 64);
    if ((tid & 63) == 0) red[tid >> 6] = s;
    __syncthreads();
    if (tid == 0) {
        float v = red[0] + red[1] + red[2] + red[3];
        atomicAdd(out, -v / (float)NROWS);
    }
}

extern "C" void kernel_launch(void* const* d_in, const int* in_sizes, int n_in,
                              void* d_out, int out_size, void* d_ws, size_t ws_size,
                              hipStream_t stream) {
    const float* emb  = (const float*)d_in[0];
    const float* W    = (const float*)d_in[1];
    const float* bias = (const float*)d_in[2];
    float* out = (float*)d_out;

    char* ws = (char*)d_ws;
    __bf16* outb  = (__bf16*)ws;                              // 4 MB normalized X
    __bf16* Wt    = (__bf16*)(ws + (4u << 20));               // 1 MB W^T bf16
    float*  total = (float*)(ws + (5u << 20));                // 32 KB
    float*  posv  = (float*)(ws + (5u << 20) + (32u << 10));  // 32 KB

    wt_kernel<<<dim3(DIM / 64, EMB / 64), 256, 0, stream>>>(W, Wt, total, out);
    gemm_norm_bf<<<dim3(NROWS / 32), 256, 0, stream>>>(emb, Wt, bias, outb);
    sim_kernel<<<dim3(NBLK), 256, 0, stream>>>(outb, total, posv);
    loss_kernel<<<dim3(NROWS / 256), 256, 0, stream>>>(total, posv, out);
}